// Round 1
// baseline (895.152 us; speedup 1.0000x reference)
//
#include <hip/hip_runtime.h>
#include <stdint.h>

// Problem constants
#define Bdim  8
#define Edim  256
#define Kdim  64
#define Hdim  768
#define NHdim 12
#define HDdim 64
// BE = 2048, M_kv = 131072

typedef __attribute__((ext_vector_type(8))) short short8;
typedef __attribute__((ext_vector_type(4))) float floatx4;
typedef unsigned short ushort_t;
typedef unsigned int u32;

__device__ __forceinline__ float bf2f(ushort_t u){
  union { u32 i; float f; } v; v.i = ((u32)u) << 16; return v.f;
}
__device__ __forceinline__ ushort_t f2bf(float f){
  union { float f; u32 i; } v; v.f = f;
  u32 r = v.i + 0x7fffu + ((v.i >> 16) & 1u);   // round-to-nearest-even
  return (ushort_t)(r >> 16);
}

// async global->LDS 16B; LDS dest is wave-uniform base + lane*16 (HW adds lane offset)
__device__ __forceinline__ void async_ld16(void* lds, const void* g){
  __builtin_amdgcn_global_load_lds(
      (const __attribute__((address_space(1))) u32*)(uintptr_t)g,
      (__attribute__((address_space(3))) u32*)(u32)(uintptr_t)lds,
      16, 0, 0);
}

// ---------------------------------------------------------------------------
// GEMM: C[M][768] = A[M][768](fp32) @ W[768][768]^T(bf16) + bias(fp32)
// tile 128x128, BK=32, 256 threads (4 waves as 2x2 of 64x64)
// STORE_BF16=1 -> bf16 C via LDS repack; 0 -> fp32 direct stores
// ---------------------------------------------------------------------------
template<int STORE_BF16>
__global__ __launch_bounds__(256, 2)
void gemm_proj(const float* __restrict__ A, const ushort_t* __restrict__ W,
               const float* __restrict__ bias, void* __restrict__ Cout)
{
  __shared__ __align__(16) char smem[34816]; // 2 x (A 8KB + W 8KB) staging; epilogue repack 128x136 bf16
  const int t    = threadIdx.x;
  const int lane = t & 63;
  const int wave = t >> 6;
  const int wm   = wave >> 1, wn = wave & 1;
  const int n0   = blockIdx.x * 128;
  const int m0   = blockIdx.y * 128;

  floatx4 acc[4][4];
#pragma unroll
  for (int i = 0; i < 4; i++)
#pragma unroll
    for (int j = 0; j < 4; j++) acc[i][j] = (floatx4)0.f;

  // A staging: 4 chunks of 4 floats per thread per K-step (128x32 fp32)
  int am[4], ac[4];
#pragma unroll
  for (int q = 0; q < 4; q++){ int idx = q*256 + t; am[q] = idx >> 3; ac[q] = idx & 7; }

  float4 areg[4];
  const int NT = Hdim / 32;   // 24 K-steps

  char* const smemc = (char*)smem;
  auto Abase = [&](int b){ return smemc + b*16384; };
  auto Wbase = [&](int b){ return smemc + b*16384 + 8192; };

  auto loadA = [&](int kt){
    const float* Ap = A + (size_t)m0*768 + kt*32;
#pragma unroll
    for (int q = 0; q < 4; q++)
      areg[q] = *(const float4*)(Ap + (size_t)am[q]*768 + ac[q]*4);
  };
  auto writeA = [&](int b){
    char* base = Abase(b);
#pragma unroll
    for (int q = 0; q < 4; q++){
      u32 lo = (u32)f2bf(areg[q].x) | ((u32)f2bf(areg[q].y) << 16);
      u32 hi = (u32)f2bf(areg[q].z) | ((u32)f2bf(areg[q].w) << 16);
      int off = am[q]*64 + ((ac[q]*8) ^ ((am[q]&3) << 4));   // XOR swizzle (16B granules)
      u32* p = (u32*)(base + off);
      p[0] = lo; p[1] = hi;
    }
  };
  auto stageW = [&](int kt, int b){
    char* base = Wbase(b);
#pragma unroll
    for (int i = 0; i < 2; i++){
      int s  = i*256 + t;          // linear 16B-chunk id in tile [128 n][4 kc]
      int n  = s >> 2, kc = s & 3;
      int kcs = kc ^ (n & 3);      // inverse-swizzled SOURCE (LDS dest stays linear)
      const ushort_t* g = W + (size_t)(n0 + n)*768 + kt*32 + kcs*8;
      char* ldst = base + (i*256 + wave*64) * 16;  // wave-uniform dest base
      async_ld16(ldst, g);
    }
  };
  auto compute = [&](int b){
    char* ab = Abase(b);
    char* wb = Wbase(b);
    short8 af[4], bf[4];
#pragma unroll
    for (int mi = 0; mi < 4; mi++){
      int row = wm*64 + mi*16 + (lane & 15);
      int off = row*64 + (((lane >> 4) * 16) ^ ((row & 3) << 4));
      af[mi] = *(const short8*)(ab + off);
    }
#pragma unroll
    for (int ni = 0; ni < 4; ni++){
      int row = wn*64 + ni*16 + (lane & 15);
      int off = row*64 + (((lane >> 4) * 16) ^ ((row & 3) << 4));
      bf[ni] = *(const short8*)(wb + off);
    }
#pragma unroll
    for (int mi = 0; mi < 4; mi++)
#pragma unroll
      for (int ni = 0; ni < 4; ni++)
        acc[mi][ni] = __builtin_amdgcn_mfma_f32_16x16x32_bf16(af[mi], bf[ni], acc[mi][ni], 0, 0, 0);
  };

  int buf = 0;
  loadA(0);
  stageW(0, 0);
  writeA(0);
  asm volatile("s_waitcnt vmcnt(0)" ::: "memory");
  __syncthreads();

  for (int kt = 0; kt < NT; ++kt){
    if (kt + 1 < NT){
      loadA(kt + 1);
      stageW(kt + 1, buf ^ 1);
    }
    compute(buf);
    if (kt + 1 < NT) writeA(buf ^ 1);
    asm volatile("s_waitcnt vmcnt(0)" ::: "memory");
    __syncthreads();
    buf ^= 1;
  }

  // epilogue
  float bvv[4];
#pragma unroll
  for (int ni = 0; ni < 4; ni++) bvv[ni] = bias[n0 + wn*64 + ni*16 + (lane & 15)];

  if (STORE_BF16){
    ushort_t* sc = (ushort_t*)smem;   // [128][136] padded
#pragma unroll
    for (int mi = 0; mi < 4; mi++){
      int row0 = wm*64 + mi*16 + ((lane >> 4) << 2);
#pragma unroll
      for (int ni = 0; ni < 4; ni++){
        int col = wn*64 + ni*16 + (lane & 15);
#pragma unroll
        for (int r = 0; r < 4; r++)
          sc[(row0 + r)*136 + col] = f2bf(acc[mi][ni][r] + bvv[ni]);
      }
    }
    __syncthreads();
    ushort_t* C = (ushort_t*)Cout;
    int row = t >> 1, seg = t & 1;
    const char* src = smemc + row*272 + seg*128;
    char* dst = (char*)(C + (size_t)(m0 + row)*768 + n0 + seg*64);
#pragma unroll
    for (int c = 0; c < 8; c++)
      *(floatx4*)(dst + c*16) = *(const floatx4*)(src + c*16);
  } else {
    float* C = (float*)Cout;
#pragma unroll
    for (int mi = 0; mi < 4; mi++){
      int row0 = wm*64 + mi*16 + ((lane >> 4) << 2);
#pragma unroll
      for (int ni = 0; ni < 4; ni++){
        int col = wn*64 + ni*16 + (lane & 15);
#pragma unroll
        for (int r = 0; r < 4; r++)
          C[(size_t)(m0 + row0 + r)*768 + n0 + col] = acc[mi][ni][r] + bvv[ni];
      }
    }
  }
}

// ---------------------------------------------------------------------------
// weights fp32 -> bf16 (589824 elements, grid 576 x 256, 4/thread)
// ---------------------------------------------------------------------------
__global__ __launch_bounds__(256)
void cvt_w(const float* __restrict__ W, ushort_t* __restrict__ O)
{
  int i = (blockIdx.x * 256 + threadIdx.x) * 4;
  float4 v = *(const float4*)(W + i);
  u32 lo = (u32)f2bf(v.x) | ((u32)f2bf(v.y) << 16);
  u32 hi = (u32)f2bf(v.z) | ((u32)f2bf(v.w) << 16);
  u32* p = (u32*)(O + i);
  p[0] = lo; p[1] = hi;
}

// ---------------------------------------------------------------------------
// scores: probs[be][h][j] = softmax_j(Qp[be,h*64:]·Kp[be*64+j,h*64:]/8) * t[be,j]
// block = one (b,e); 4 waves x 3 heads; lane = j
// ---------------------------------------------------------------------------
__global__ __launch_bounds__(256)
void attn_scores(const float* __restrict__ Qp, const ushort_t* __restrict__ Kp,
                 const float* __restrict__ tsc, float* __restrict__ probs)
{
  const int be = blockIdx.x;
  const int t = threadIdx.x, lane = t & 63, wave = t >> 6;
  __shared__ float qf[768];
  for (int i = t; i < 768; i += 256) qf[i] = Qp[(size_t)be*768 + i];
  __syncthreads();
  const float tj = tsc[be*64 + lane];
  for (int h = wave; h < NHdim; h += 4){
    const ushort_t* krow = Kp + (size_t)(be*64 + lane)*768 + h*64;
    float s = 0.f;
#pragma unroll
    for (int c = 0; c < 8; c++){
      short8 kv = *(const short8*)(krow + c*8);
#pragma unroll
      for (int e = 0; e < 8; e++)
        s += qf[h*64 + c*8 + e] * bf2f((ushort_t)kv[e]);
    }
    s *= 0.125f;   // 1/sqrt(64)
    float mx = s;
#pragma unroll
    for (int off = 32; off; off >>= 1) mx = fmaxf(mx, __shfl_xor(mx, off));
    float p = __expf(s - mx);
    float sum = p;
#pragma unroll
    for (int off = 32; off; off >>= 1) sum += __shfl_xor(sum, off);
    probs[((size_t)be*NHdim + h)*64 + lane] = p / sum * tj;
  }
}

// ---------------------------------------------------------------------------
// pv: out[be][h*64+d] = sum_j probs[be][h][j] * Vp[be*64+j][h*64+d]
// block = one (b,e); 4 waves x 3 heads; lane = d
// ---------------------------------------------------------------------------
__global__ __launch_bounds__(256)
void attn_pv(const ushort_t* __restrict__ Vp, const float* __restrict__ probs,
             float* __restrict__ out)
{
  const int be = blockIdx.x;
  const int t = threadIdx.x, lane = t & 63, wave = t >> 6;
  __shared__ float pr[768];
  for (int i = t; i < 768; i += 256) pr[i] = probs[(size_t)be*768 + i];
  __syncthreads();
  for (int h = wave; h < NHdim; h += 4){
    const ushort_t* vp = Vp + (size_t)be*64*768 + h*64 + lane;
    float ctx = 0.f;
#pragma unroll 8
    for (int j = 0; j < 64; j++)
      ctx += pr[h*64 + j] * bf2f(vp[(size_t)j*768]);
    out[(size_t)be*768 + h*64 + lane] = ctx;
  }
}

// ---------------------------------------------------------------------------
extern "C" void kernel_launch(void* const* d_in, const int* in_sizes, int n_in,
                              void* d_out, int out_size, void* d_ws, size_t ws_size,
                              hipStream_t stream)
{
  const float* q_in = (const float*)d_in[0];
  const float* k_in = (const float*)d_in[1];
  const float* v_in = (const float*)d_in[2];
  const float* tsc  = (const float*)d_in[3];
  const float* Wq   = (const float*)d_in[4];
  const float* bq   = (const float*)d_in[5];
  const float* Wk   = (const float*)d_in[6];
  const float* bk   = (const float*)d_in[7];
  const float* Wv   = (const float*)d_in[8];
  const float* bv   = (const float*)d_in[9];

  // ws layout (bytes):
  //   0        Wq bf16   (1179648)
  //   1179648  Wk bf16
  //   2359296  Wv bf16
  //   3538944  Qp fp32   (2048*768*4 = 6291456)
  //   9830400  probs fp32(2048*12*64*4 = 6291456)
  //   16121856 P bf16    (131072*768*2 = 201326592)  -- Kp then reused for Vp
  // total ~207.4 MiB
  char* ws = (char*)d_ws;
  ushort_t* Wqb = (ushort_t*)(ws);
  ushort_t* Wkb = (ushort_t*)(ws + 1179648);
  ushort_t* Wvb = (ushort_t*)(ws + 2359296);
  float*    Qp  = (float*)   (ws + 3538944);
  float*    Pr  = (float*)   (ws + 9830400);
  ushort_t* P   = (ushort_t*)(ws + 16121856);

  cvt_w<<<576, 256, 0, stream>>>(Wq, Wqb);
  cvt_w<<<576, 256, 0, stream>>>(Wk, Wkb);
  cvt_w<<<576, 256, 0, stream>>>(Wv, Wvb);

  // Q projection: M=2048, fp32 output (keeps score precision)
  gemm_proj<0><<<dim3(6, 16),   256, 0, stream>>>(q_in, Wqb, bq, (void*)Qp);
  // K projection: M=131072, bf16 output
  gemm_proj<1><<<dim3(6, 1024), 256, 0, stream>>>(k_in, Wkb, bk, (void*)P);
  attn_scores<<<2048, 256, 0, stream>>>(Qp, P, tsc, Pr);
  // V projection overwrites the same P region (stream-ordered after attn_scores)
  gemm_proj<1><<<dim3(6, 1024), 256, 0, stream>>>(v_in, Wvb, bv, (void*)P);
  attn_pv<<<2048, 256, 0, stream>>>(P, Pr, (float*)d_out);
}

// Round 4
// 505.743 us; speedup vs baseline: 1.7700x; 1.7700x over previous
//
#include <hip/hip_runtime.h>
#include <stdint.h>

// Problem constants
#define Bdim  8
#define Edim  256
#define Kdim  64
#define Hdim  768
#define NHdim 12
#define HDdim 64
// BE = 2048

typedef __attribute__((ext_vector_type(8))) short short8;
typedef __attribute__((ext_vector_type(4))) float floatx4;
typedef unsigned short ushort_t;
typedef unsigned int u32;

#define GPLANE (2048*768)   // g plane stride (elements) per head

__device__ __forceinline__ float bf2f(ushort_t u){
  union { u32 i; float f; } v; v.i = ((u32)u) << 16; return v.f;
}
__device__ __forceinline__ ushort_t f2bf(float f){
  union { float f; u32 i; } v; v.f = f;
  u32 r = v.i + 0x7fffu + ((v.i >> 16) & 1u);   // RNE
  return (ushort_t)(r >> 16);
}

// async global->LDS 16B (dest: wave-uniform base + lane*16)
__device__ __forceinline__ void async_ld16(void* lds, const void* g){
  __builtin_amdgcn_global_load_lds(
      (const __attribute__((address_space(1))) u32*)(uintptr_t)g,
      (__attribute__((address_space(3))) u32*)(u32)(uintptr_t)lds,
      16, 0, 0);
}

// ---------------------------------------------------------------------------
// GEMM (verified round-1): C[M][768] = A[M][768](fp32) @ W^T(bf16) + bias
// 128x128 tile, BK=32, 4 waves. STORE_BF16 selects output dtype.
// ---------------------------------------------------------------------------
template<int STORE_BF16>
__global__ __launch_bounds__(256, 2)
void gemm_proj(const float* __restrict__ A, const ushort_t* __restrict__ W,
               const float* __restrict__ bias, void* __restrict__ Cout)
{
  __shared__ __align__(16) char smem[34816];
  const int t    = threadIdx.x;
  const int lane = t & 63;
  const int wave = t >> 6;
  const int wm   = wave >> 1, wn = wave & 1;
  const int n0   = blockIdx.x * 128;
  const int m0   = blockIdx.y * 128;

  floatx4 acc[4][4];
#pragma unroll
  for (int i = 0; i < 4; i++)
#pragma unroll
    for (int j = 0; j < 4; j++) acc[i][j] = (floatx4)0.f;

  int am[4], ac[4];
#pragma unroll
  for (int q = 0; q < 4; q++){ int idx = q*256 + t; am[q] = idx >> 3; ac[q] = idx & 7; }

  float4 areg[4];
  const int NT = Hdim / 32;

  char* const smemc = (char*)smem;
  auto Abase = [&](int b){ return smemc + b*16384; };
  auto Wbase = [&](int b){ return smemc + b*16384 + 8192; };

  auto loadA = [&](int kt){
    const float* Ap = A + (size_t)m0*768 + kt*32;
#pragma unroll
    for (int q = 0; q < 4; q++)
      areg[q] = *(const float4*)(Ap + (size_t)am[q]*768 + ac[q]*4);
  };
  auto writeA = [&](int b){
    char* base = Abase(b);
#pragma unroll
    for (int q = 0; q < 4; q++){
      u32 lo = (u32)f2bf(areg[q].x) | ((u32)f2bf(areg[q].y) << 16);
      u32 hi = (u32)f2bf(areg[q].z) | ((u32)f2bf(areg[q].w) << 16);
      int off = am[q]*64 + ((ac[q]*8) ^ ((am[q]&3) << 4));
      u32* p = (u32*)(base + off);
      p[0] = lo; p[1] = hi;
    }
  };
  auto stageW = [&](int kt, int b){
    char* base = Wbase(b);
#pragma unroll
    for (int i = 0; i < 2; i++){
      int s  = i*256 + t;
      int n  = s >> 2, kc = s & 3;
      int kcs = kc ^ (n & 3);
      const ushort_t* g = W + (size_t)(n0 + n)*768 + kt*32 + kcs*8;
      char* ldst = base + (i*256 + wave*64) * 16;
      async_ld16(ldst, g);
    }
  };
  auto compute = [&](int b){
    char* ab = Abase(b);
    char* wb = Wbase(b);
    short8 af[4], bf[4];
#pragma unroll
    for (int mi = 0; mi < 4; mi++){
      int row = wm*64 + mi*16 + (lane & 15);
      int off = row*64 + (((lane >> 4) * 16) ^ ((row & 3) << 4));
      af[mi] = *(const short8*)(ab + off);
    }
#pragma unroll
    for (int ni = 0; ni < 4; ni++){
      int row = wn*64 + ni*16 + (lane & 15);
      int off = row*64 + (((lane >> 4) * 16) ^ ((row & 3) << 4));
      bf[ni] = *(const short8*)(wb + off);
    }
#pragma unroll
    for (int mi = 0; mi < 4; mi++)
#pragma unroll
      for (int ni = 0; ni < 4; ni++)
        acc[mi][ni] = __builtin_amdgcn_mfma_f32_16x16x32_bf16(af[mi], bf[ni], acc[mi][ni], 0, 0, 0);
  };

  int buf = 0;
  loadA(0);
  stageW(0, 0);
  writeA(0);
  asm volatile("s_waitcnt vmcnt(0)" ::: "memory");
  __syncthreads();

  for (int kt = 0; kt < NT; ++kt){
    if (kt + 1 < NT){
      loadA(kt + 1);
      stageW(kt + 1, buf ^ 1);
    }
    compute(buf);
    if (kt + 1 < NT) writeA(buf ^ 1);
    asm volatile("s_waitcnt vmcnt(0)" ::: "memory");
    __syncthreads();
    buf ^= 1;
  }

  float bvv[4];
#pragma unroll
  for (int ni = 0; ni < 4; ni++) bvv[ni] = bias[n0 + wn*64 + ni*16 + (lane & 15)];

  if (STORE_BF16){
    ushort_t* sc = (ushort_t*)smem;
#pragma unroll
    for (int mi = 0; mi < 4; mi++){
      int row0 = wm*64 + mi*16 + ((lane >> 4) << 2);
#pragma unroll
      for (int ni = 0; ni < 4; ni++){
        int col = wn*64 + ni*16 + (lane & 15);
#pragma unroll
        for (int r = 0; r < 4; r++)
          sc[(row0 + r)*136 + col] = f2bf(acc[mi][ni][r] + bvv[ni]);
      }
    }
    __syncthreads();
    ushort_t* C = (ushort_t*)Cout;
    int row = t >> 1, seg = t & 1;
    const char* src = smemc + row*272 + seg*128;
    char* dst = (char*)(C + (size_t)(m0 + row)*768 + n0 + seg*64);
#pragma unroll
    for (int c = 0; c < 8; c++)
      *(floatx4*)(dst + c*16) = *(const floatx4*)(src + c*16);
  } else {
    float* C = (float*)Cout;
#pragma unroll
    for (int mi = 0; mi < 4; mi++){
      int row0 = wm*64 + mi*16 + ((lane >> 4) << 2);
#pragma unroll
      for (int ni = 0; ni < 4; ni++){
        int col = wn*64 + ni*16 + (lane & 15);
#pragma unroll
        for (int r = 0; r < 4; r++)
          C[(size_t)(m0 + row0 + r)*768 + n0 + col] = acc[mi][ni][r] + bvv[ni];
      }
    }
  }
}

// ---------------------------------------------------------------------------
// fp32 -> bf16 weight convert (589824 elems)
// ---------------------------------------------------------------------------
__global__ __launch_bounds__(256)
void cvt_w(const float* __restrict__ W, ushort_t* __restrict__ O)
{
  int i = (blockIdx.x * 256 + threadIdx.x) * 4;
  float4 v = *(const float4*)(W + i);
  u32 lo = (u32)f2bf(v.x) | ((u32)f2bf(v.y) << 16);
  u32 hi = (u32)f2bf(v.z) | ((u32)f2bf(v.w) << 16);
  u32* p = (u32*)(O + i);
  p[0] = lo; p[1] = hi;
}

// transpose + convert: O[c][o] = bf16(W[o][c]); 768x768, 32x32 tiles
__global__ __launch_bounds__(256)
void cvt_wT(const float* __restrict__ W, ushort_t* __restrict__ O)
{
  __shared__ float tile[32][33];
  int bo = blockIdx.x * 32;   // o (rows of W)
  int bc = blockIdx.y * 32;   // c (cols of W)
  int tx = threadIdx.x & 31, ty = threadIdx.x >> 5;
#pragma unroll
  for (int i = 0; i < 4; i++)
    tile[ty + 8*i][tx] = W[(size_t)(bo + ty + 8*i)*768 + bc + tx];
  __syncthreads();
#pragma unroll
  for (int i = 0; i < 4; i++)
    O[(size_t)(bc + ty + 8*i)*768 + bo + tx] = f2bf(tile[tx][ty + 8*i]);
}

// ---------------------------------------------------------------------------
// g[h][be][c] = sum_d qp[be][h*64+d] * WkT[c][h*64+d]   (bf16 in/out, K=64)
// tile 128(be) x 128(c); no LDS staging (A/B tiles from L1/L2 direct)
// ---------------------------------------------------------------------------
__global__ __launch_bounds__(256)
void gemm_g(const ushort_t* __restrict__ qp, const ushort_t* __restrict__ WkT,
            ushort_t* __restrict__ g)
{
  const int h  = blockIdx.z;
  const int n0 = blockIdx.x * 128;   // c
  const int m0 = blockIdx.y * 128;   // be
  const int t = threadIdx.x, lane = t & 63, wave = t >> 6;
  const int wm = wave >> 1, wn = wave & 1;
  const int hl = lane & 15, jr = lane >> 4;

  floatx4 acc[4][4];
#pragma unroll
  for (int i = 0; i < 4; i++)
#pragma unroll
    for (int j = 0; j < 4; j++) acc[i][j] = (floatx4)0.f;

#pragma unroll
  for (int kt = 0; kt < 2; kt++){
    short8 af[4], bf[4];
#pragma unroll
    for (int mi = 0; mi < 4; mi++)
      af[mi] = *(const short8*)(qp + (size_t)(m0 + wm*64 + mi*16 + hl)*768 + h*64 + kt*32 + jr*8);
#pragma unroll
    for (int ni = 0; ni < 4; ni++)
      bf[ni] = *(const short8*)(WkT + (size_t)(n0 + wn*64 + ni*16 + hl)*768 + h*64 + kt*32 + jr*8);
#pragma unroll
    for (int mi = 0; mi < 4; mi++)
#pragma unroll
      for (int ni = 0; ni < 4; ni++)
        acc[mi][ni] = __builtin_amdgcn_mfma_f32_16x16x32_bf16(af[mi], bf[ni], acc[mi][ni], 0, 0, 0);
  }

  ushort_t* gp = g + (size_t)h * GPLANE;
#pragma unroll
  for (int mi = 0; mi < 4; mi++){
#pragma unroll
    for (int ni = 0; ni < 4; ni++){
      int col = n0 + wn*64 + ni*16 + hl;
#pragma unroll
      for (int r = 0; r < 4; r++){
        int row = m0 + wm*64 + mi*16 + jr*4 + r;
        gp[(size_t)row*768 + col] = f2bf(acc[mi][ni][r]);
      }
    }
  }
}

// ---------------------------------------------------------------------------
// Fused attention: one block per (b,e).
//  scores (MFMA, k_in fp32->bf16 in-reg, g as B) -> softmax*type -> u (VALU)
//  -> out[o] = u[h]·Wv[o,:] + bv[o]*ps[h]
// ---------------------------------------------------------------------------
__global__ __launch_bounds__(256)
void attn_fused(const float* __restrict__ k_in, const float* __restrict__ v_in,
                const float* __restrict__ tsc, const ushort_t* __restrict__ g,
                const ushort_t* __restrict__ Wv, const float* __restrict__ bv,
                float* __restrict__ out)
{
  const int be = blockIdx.x;
  const int t = threadIdx.x, lane = t & 63, w = t >> 6;
  const int hl = lane & 15, jr = lane >> 4;

  __shared__ float P[12][64];        // final probs (softmax * type)
  __shared__ float U[12][768];       // u vectors
  __shared__ float red[4][16];
  __shared__ float psl[16];

  // ---- scores: D[16 j x 16 h] per wave, contraction over c=768 ----
  const float* krow = k_in + (size_t)be*Kdim*768 + (size_t)(w*16 + hl)*768;
  const int hq = (hl < 12) ? hl : 0;
  const ushort_t* grow = g + (size_t)hq*GPLANE + (size_t)be*768;

  floatx4 acc = (floatx4)0.f;
#pragma unroll 4
  for (int kt = 0; kt < 24; kt++){
    int c0 = kt*32 + jr*8;
    float4 f0 = *(const float4*)(krow + c0);
    float4 f1 = *(const float4*)(krow + c0 + 4);
    short8 af;
    af[0]=(short)f2bf(f0.x); af[1]=(short)f2bf(f0.y); af[2]=(short)f2bf(f0.z); af[3]=(short)f2bf(f0.w);
    af[4]=(short)f2bf(f1.x); af[5]=(short)f2bf(f1.y); af[6]=(short)f2bf(f1.z); af[7]=(short)f2bf(f1.w);
    short8 bf = *(const short8*)(grow + c0);
    acc = __builtin_amdgcn_mfma_f32_16x16x32_bf16(af, bf, acc, 0, 0, 0);
  }

  // lane holds scores[j = w*16 + jr*4 + r][h = hl], r=0..3
  float s[4];
#pragma unroll
  for (int r = 0; r < 4; r++) s[r] = acc[r] * 0.125f;

  // ---- softmax over j (64), then * type_score ----
  float wmax = fmaxf(fmaxf(s[0], s[1]), fmaxf(s[2], s[3]));
  wmax = fmaxf(wmax, __shfl_xor(wmax, 16));
  wmax = fmaxf(wmax, __shfl_xor(wmax, 32));
  if (jr == 0) red[w][hl] = wmax;
  __syncthreads();
  float gm = fmaxf(fmaxf(red[0][hl], red[1][hl]), fmaxf(red[2][hl], red[3][hl]));

  float e[4], es = 0.f;
#pragma unroll
  for (int r = 0; r < 4; r++){ e[r] = __expf(s[r] - gm); es += e[r]; }
  es += __shfl_xor(es, 16);
  es += __shfl_xor(es, 32);
  __syncthreads();
  if (jr == 0) red[w][hl] = es;
  __syncthreads();
  float S = red[0][hl] + red[1][hl] + red[2][hl] + red[3][hl];
  float invS = 1.0f / S;

  float4 t4 = *(const float4*)(tsc + be*64 + w*16 + jr*4);
  float p[4];
  p[0] = e[0]*invS*t4.x; p[1] = e[1]*invS*t4.y; p[2] = e[2]*invS*t4.z; p[3] = e[3]*invS*t4.w;
  float psum = p[0]+p[1]+p[2]+p[3];
  psum += __shfl_xor(psum, 16);
  psum += __shfl_xor(psum, 32);
  __syncthreads();
  if (jr == 0) red[w][hl] = psum;
  __syncthreads();
  float psh = red[0][hl] + red[1][hl] + red[2][hl] + red[3][hl];

  if (hl < 12){
    *(float4*)&P[hl][w*16 + jr*4] = make_float4(p[0], p[1], p[2], p[3]);
    if (w == 0 && jr == 0) psl[hl] = psh;
  }
  __syncthreads();

  // ---- u[h][c] = sum_j P[h][j] * v_in[j][c]; thread owns c = t, t+256, t+512 ----
  const float* vbase = v_in + (size_t)be*Kdim*768;
  float u[12][3];
#pragma unroll
  for (int h = 0; h < 12; h++){ u[h][0]=0.f; u[h][1]=0.f; u[h][2]=0.f; }

  for (int jb = 0; jb < 16; jb++){
    float v0[4], v1[4], v2[4];
#pragma unroll
    for (int q = 0; q < 4; q++){
      const float* vr = vbase + (size_t)(jb*4 + q)*768;
      v0[q] = vr[t]; v1[q] = vr[t + 256]; v2[q] = vr[t + 512];
    }
#pragma unroll
    for (int h = 0; h < 12; h++){
      float4 p4 = *(const float4*)&P[h][jb*4];
      u[h][0] += p4.x*v0[0] + p4.y*v0[1] + p4.z*v0[2] + p4.w*v0[3];
      u[h][1] += p4.x*v1[0] + p4.y*v1[1] + p4.z*v1[2] + p4.w*v1[3];
      u[h][2] += p4.x*v2[0] + p4.y*v2[1] + p4.z*v2[2] + p4.w*v2[3];
    }
  }
#pragma unroll
  for (int h = 0; h < 12; h++){
    U[h][t] = u[h][0]; U[h][t+256] = u[h][1]; U[h][t+512] = u[h][2];
  }
  __syncthreads();

  // ---- out[o] = sum_c U[h(o)][c] * Wv[o][c] + bv[o]*ps[h]; o = t + 256k ----
#pragma unroll
  for (int k = 0; k < 3; k++){
    int o = t + 256*k;
    int h = o >> 6;
    const ushort_t* wrow = Wv + (size_t)o*768;
    float a0 = 0.f, a1 = 0.f;
    for (int cb = 0; cb < 96; cb++){
      short8 w8 = *(const short8*)(wrow + cb*8);
      float4 ua = *(const float4*)&U[h][cb*8];
      float4 ub = *(const float4*)&U[h][cb*8 + 4];
      a0 += bf2f((ushort_t)w8[0])*ua.x + bf2f((ushort_t)w8[1])*ua.y
          + bf2f((ushort_t)w8[2])*ua.z + bf2f((ushort_t)w8[3])*ua.w;
      a1 += bf2f((ushort_t)w8[4])*ub.x + bf2f((ushort_t)w8[5])*ub.y
          + bf2f((ushort_t)w8[6])*ub.z + bf2f((ushort_t)w8[7])*ub.w;
    }
    out[(size_t)be*768 + o] = a0 + a1 + bv[o]*psl[h];
  }
}

// ---------------------------------------------------------------------------
extern "C" void kernel_launch(void* const* d_in, const int* in_sizes, int n_in,
                              void* d_out, int out_size, void* d_ws, size_t ws_size,
                              hipStream_t stream)
{
  const float* q_in = (const float*)d_in[0];
  const float* k_in = (const float*)d_in[1];
  const float* v_in = (const float*)d_in[2];
  const float* tsc  = (const float*)d_in[3];
  const float* Wq   = (const float*)d_in[4];
  const float* bq   = (const float*)d_in[5];
  const float* Wk   = (const float*)d_in[6];
  // const float* bk = (const float*)d_in[7];   // softmax-invariant, dropped
  const float* Wv   = (const float*)d_in[8];
  const float* bv   = (const float*)d_in[9];

  // ws layout (bytes):
  //   0        Wq bf16    1179648
  //   1179648  Wv bf16    1179648
  //   2359296  WkT bf16   1179648
  //   3538944  qp bf16    3145728   (2048 x 768)
  //   6684672  g bf16     37748736  (12 x 2048 x 768, plane-major [h][be][c])
  // total ~42.4 MiB
  char* ws = (char*)d_ws;
  ushort_t* Wqb  = (ushort_t*)(ws);
  ushort_t* Wvb  = (ushort_t*)(ws + 1179648);
  ushort_t* WkTb = (ushort_t*)(ws + 2359296);
  ushort_t* qp   = (ushort_t*)(ws + 3538944);
  ushort_t* g    = (ushort_t*)(ws + 6684672);

  cvt_w <<<576, 256, 0, stream>>>(Wq, Wqb);
  cvt_w <<<576, 256, 0, stream>>>(Wv, Wvb);
  cvt_wT<<<dim3(24, 24), 256, 0, stream>>>(Wk, WkTb);

  // qp = q_in @ Wq^T + bq  (bf16 out), M=2048
  gemm_proj<1><<<dim3(6, 16), 256, 0, stream>>>(q_in, Wqb, bq, (void*)qp);

  // g[h] = qp_h @ Wk_h (per-head, K=64)
  gemm_g<<<dim3(6, 16, 12), 256, 0, stream>>>(qp, WkTb, g);

  // fused scores/softmax/u/out
  attn_fused<<<2048, 256, 0, stream>>>(k_in, v_in, tsc, g, Wvb, bv, (float*)d_out);
}

// Round 5
// 269.674 us; speedup vs baseline: 3.3194x; 1.8754x over previous
//
#include <hip/hip_runtime.h>
#include <stdint.h>

// Problem constants
#define Bdim  8
#define Edim  256
#define Kdim  64
#define Hdim  768
#define NHdim 12
#define HDdim 64
// BE = 2048

typedef __attribute__((ext_vector_type(8))) short short8;
typedef __attribute__((ext_vector_type(4))) float floatx4;
typedef unsigned short ushort_t;
typedef unsigned int u32;

#define GPLANE (2048*768)   // per-head plane stride (elements) for g and U

__device__ __forceinline__ float bf2f(ushort_t u){
  union { u32 i; float f; } v; v.i = ((u32)u) << 16; return v.f;
}
__device__ __forceinline__ ushort_t f2bf(float f){
  union { float f; u32 i; } v; v.f = f;
  u32 r = v.i + 0x7fffu + ((v.i >> 16) & 1u);   // RNE
  return (ushort_t)(r >> 16);
}

// async global->LDS 16B (dest: wave-uniform base + lane*16)
__device__ __forceinline__ void async_ld16(void* lds, const void* g){
  __builtin_amdgcn_global_load_lds(
      (const __attribute__((address_space(1))) u32*)(uintptr_t)g,
      (__attribute__((address_space(3))) u32*)(u32)(uintptr_t)lds,
      16, 0, 0);
}

// ---------------------------------------------------------------------------
// GEMM (verified): C[M][768] = A[M][768](fp32) @ W^T(bf16) + bias
// ---------------------------------------------------------------------------
template<int STORE_BF16>
__global__ __launch_bounds__(256, 2)
void gemm_proj(const float* __restrict__ A, const ushort_t* __restrict__ W,
               const float* __restrict__ bias, void* __restrict__ Cout)
{
  __shared__ __align__(16) char smem[34816];
  const int t    = threadIdx.x;
  const int lane = t & 63;
  const int wave = t >> 6;
  const int wm   = wave >> 1, wn = wave & 1;
  const int n0   = blockIdx.x * 128;
  const int m0   = blockIdx.y * 128;

  floatx4 acc[4][4];
#pragma unroll
  for (int i = 0; i < 4; i++)
#pragma unroll
    for (int j = 0; j < 4; j++) acc[i][j] = (floatx4)0.f;

  int am[4], ac[4];
#pragma unroll
  for (int q = 0; q < 4; q++){ int idx = q*256 + t; am[q] = idx >> 3; ac[q] = idx & 7; }

  float4 areg[4];
  const int NT = Hdim / 32;

  char* const smemc = (char*)smem;
  auto Abase = [&](int b){ return smemc + b*16384; };
  auto Wbase = [&](int b){ return smemc + b*16384 + 8192; };

  auto loadA = [&](int kt){
    const float* Ap = A + (size_t)m0*768 + kt*32;
#pragma unroll
    for (int q = 0; q < 4; q++)
      areg[q] = *(const float4*)(Ap + (size_t)am[q]*768 + ac[q]*4);
  };
  auto writeA = [&](int b){
    char* base = Abase(b);
#pragma unroll
    for (int q = 0; q < 4; q++){
      u32 lo = (u32)f2bf(areg[q].x) | ((u32)f2bf(areg[q].y) << 16);
      u32 hi = (u32)f2bf(areg[q].z) | ((u32)f2bf(areg[q].w) << 16);
      int off = am[q]*64 + ((ac[q]*8) ^ ((am[q]&3) << 4));
      u32* p = (u32*)(base + off);
      p[0] = lo; p[1] = hi;
    }
  };
  auto stageW = [&](int kt, int b){
    char* base = Wbase(b);
#pragma unroll
    for (int i = 0; i < 2; i++){
      int s  = i*256 + t;
      int n  = s >> 2, kc = s & 3;
      int kcs = kc ^ (n & 3);
      const ushort_t* g = W + (size_t)(n0 + n)*768 + kt*32 + kcs*8;
      char* ldst = base + (i*256 + wave*64) * 16;
      async_ld16(ldst, g);
    }
  };
  auto compute = [&](int b){
    char* ab = Abase(b);
    char* wb = Wbase(b);
    short8 af[4], bf[4];
#pragma unroll
    for (int mi = 0; mi < 4; mi++){
      int row = wm*64 + mi*16 + (lane & 15);
      int off = row*64 + (((lane >> 4) * 16) ^ ((row & 3) << 4));
      af[mi] = *(const short8*)(ab + off);
    }
#pragma unroll
    for (int ni = 0; ni < 4; ni++){
      int row = wn*64 + ni*16 + (lane & 15);
      int off = row*64 + (((lane >> 4) * 16) ^ ((row & 3) << 4));
      bf[ni] = *(const short8*)(wb + off);
    }
#pragma unroll
    for (int mi = 0; mi < 4; mi++)
#pragma unroll
      for (int ni = 0; ni < 4; ni++)
        acc[mi][ni] = __builtin_amdgcn_mfma_f32_16x16x32_bf16(af[mi], bf[ni], acc[mi][ni], 0, 0, 0);
  };

  int buf = 0;
  loadA(0);
  stageW(0, 0);
  writeA(0);
  asm volatile("s_waitcnt vmcnt(0)" ::: "memory");
  __syncthreads();

  for (int kt = 0; kt < NT; ++kt){
    if (kt + 1 < NT){
      loadA(kt + 1);
      stageW(kt + 1, buf ^ 1);
    }
    compute(buf);
    if (kt + 1 < NT) writeA(buf ^ 1);
    asm volatile("s_waitcnt vmcnt(0)" ::: "memory");
    __syncthreads();
    buf ^= 1;
  }

  float bvv[4];
#pragma unroll
  for (int ni = 0; ni < 4; ni++) bvv[ni] = bias[n0 + wn*64 + ni*16 + (lane & 15)];

  if (STORE_BF16){
    ushort_t* sc = (ushort_t*)smem;
#pragma unroll
    for (int mi = 0; mi < 4; mi++){
      int row0 = wm*64 + mi*16 + ((lane >> 4) << 2);
#pragma unroll
      for (int ni = 0; ni < 4; ni++){
        int col = wn*64 + ni*16 + (lane & 15);
#pragma unroll
        for (int r = 0; r < 4; r++)
          sc[(row0 + r)*136 + col] = f2bf(acc[mi][ni][r] + bvv[ni]);
      }
    }
    __syncthreads();
    ushort_t* C = (ushort_t*)Cout;
    int row = t >> 1, seg = t & 1;
    const char* src = smemc + row*272 + seg*128;
    char* dst = (char*)(C + (size_t)(m0 + row)*768 + n0 + seg*64);
#pragma unroll
    for (int c = 0; c < 8; c++)
      *(floatx4*)(dst + c*16) = *(const floatx4*)(src + c*16);
  } else {
    float* C = (float*)Cout;
#pragma unroll
    for (int mi = 0; mi < 4; mi++){
      int row0 = wm*64 + mi*16 + ((lane >> 4) << 2);
#pragma unroll
      for (int ni = 0; ni < 4; ni++){
        int col = wn*64 + ni*16 + (lane & 15);
#pragma unroll
        for (int r = 0; r < 4; r++)
          C[(size_t)(m0 + row0 + r)*768 + n0 + col] = acc[mi][ni][r] + bvv[ni];
      }
    }
  }
}

// ---------------------------------------------------------------------------
// fp32 -> bf16 weight convert
// ---------------------------------------------------------------------------
__global__ __launch_bounds__(256)
void cvt_w(const float* __restrict__ W, ushort_t* __restrict__ O)
{
  int i = (blockIdx.x * 256 + threadIdx.x) * 4;
  float4 v = *(const float4*)(W + i);
  u32 lo = (u32)f2bf(v.x) | ((u32)f2bf(v.y) << 16);
  u32 hi = (u32)f2bf(v.z) | ((u32)f2bf(v.w) << 16);
  u32* p = (u32*)(O + i);
  p[0] = lo; p[1] = hi;
}

// transpose + convert: O[c][o] = bf16(W[o][c])
__global__ __launch_bounds__(256)
void cvt_wT(const float* __restrict__ W, ushort_t* __restrict__ O)
{
  __shared__ float tile[32][33];
  int bo = blockIdx.x * 32;
  int bc = blockIdx.y * 32;
  int tx = threadIdx.x & 31, ty = threadIdx.x >> 5;
#pragma unroll
  for (int i = 0; i < 4; i++)
    tile[ty + 8*i][tx] = W[(size_t)(bo + ty + 8*i)*768 + bc + tx];
  __syncthreads();
#pragma unroll
  for (int i = 0; i < 4; i++)
    O[(size_t)(bc + ty + 8*i)*768 + bo + tx] = f2bf(tile[tx][ty + 8*i]);
}

// ---------------------------------------------------------------------------
// g[h][be][c] = sum_d qp[be][h*64+d] * WkT[c][h*64+d]   (bf16, K=64)
// ---------------------------------------------------------------------------
__global__ __launch_bounds__(256)
void gemm_g(const ushort_t* __restrict__ qp, const ushort_t* __restrict__ WkT,
            ushort_t* __restrict__ g)
{
  const int h  = blockIdx.z;
  const int n0 = blockIdx.x * 128;
  const int m0 = blockIdx.y * 128;
  const int t = threadIdx.x, lane = t & 63, wave = t >> 6;
  const int wm = wave >> 1, wn = wave & 1;
  const int hl = lane & 15, jr = lane >> 4;

  floatx4 acc[4][4];
#pragma unroll
  for (int i = 0; i < 4; i++)
#pragma unroll
    for (int j = 0; j < 4; j++) acc[i][j] = (floatx4)0.f;

#pragma unroll
  for (int kt = 0; kt < 2; kt++){
    short8 af[4], bf[4];
#pragma unroll
    for (int mi = 0; mi < 4; mi++)
      af[mi] = *(const short8*)(qp + (size_t)(m0 + wm*64 + mi*16 + hl)*768 + h*64 + kt*32 + jr*8);
#pragma unroll
    for (int ni = 0; ni < 4; ni++)
      bf[ni] = *(const short8*)(WkT + (size_t)(n0 + wn*64 + ni*16 + hl)*768 + h*64 + kt*32 + jr*8);
#pragma unroll
    for (int mi = 0; mi < 4; mi++)
#pragma unroll
      for (int ni = 0; ni < 4; ni++)
        acc[mi][ni] = __builtin_amdgcn_mfma_f32_16x16x32_bf16(af[mi], bf[ni], acc[mi][ni], 0, 0, 0);
  }

  ushort_t* gp = g + (size_t)h * GPLANE;
#pragma unroll
  for (int mi = 0; mi < 4; mi++){
#pragma unroll
    for (int ni = 0; ni < 4; ni++){
      int col = n0 + wn*64 + ni*16 + hl;
#pragma unroll
      for (int r = 0; r < 4; r++){
        int row = m0 + wm*64 + mi*16 + jr*4 + r;
        gp[(size_t)row*768 + col] = f2bf(acc[mi][ni][r]);
      }
    }
  }
}

// ---------------------------------------------------------------------------
// Kernel A: scores + softmax * type -> P[be][h][64] fp32
// one block per be; tiny LDS -> 8 blocks/CU
// ---------------------------------------------------------------------------
__global__ __launch_bounds__(256)
void attn_scores(const float* __restrict__ k_in, const float* __restrict__ tsc,
                 const ushort_t* __restrict__ g, float* __restrict__ probs)
{
  const int be = blockIdx.x;
  const int t = threadIdx.x, lane = t & 63, w = t >> 6;
  const int hl = lane & 15, jr = lane >> 4;

  __shared__ float redmax[4][16];
  __shared__ float redsum[4][16];

  const float* krow = k_in + (size_t)be*Kdim*768 + (size_t)(w*16 + hl)*768;
  const int hq = (hl < 12) ? hl : 0;
  const ushort_t* grow = g + (size_t)hq*GPLANE + (size_t)be*768;

  floatx4 acc = (floatx4)0.f;
#pragma unroll 4
  for (int kt = 0; kt < 24; kt++){
    int c0 = kt*32 + jr*8;
    float4 f0 = *(const float4*)(krow + c0);
    float4 f1 = *(const float4*)(krow + c0 + 4);
    short8 af;
    af[0]=(short)f2bf(f0.x); af[1]=(short)f2bf(f0.y); af[2]=(short)f2bf(f0.z); af[3]=(short)f2bf(f0.w);
    af[4]=(short)f2bf(f1.x); af[5]=(short)f2bf(f1.y); af[6]=(short)f2bf(f1.z); af[7]=(short)f2bf(f1.w);
    short8 bf = *(const short8*)(grow + c0);
    acc = __builtin_amdgcn_mfma_f32_16x16x32_bf16(af, bf, acc, 0, 0, 0);
  }

  // lane holds scores[j = w*16 + jr*4 + r][h = hl]
  float s[4];
#pragma unroll
  for (int r = 0; r < 4; r++) s[r] = acc[r] * 0.125f;

  float wmax = fmaxf(fmaxf(s[0], s[1]), fmaxf(s[2], s[3]));
  wmax = fmaxf(wmax, __shfl_xor(wmax, 16));
  wmax = fmaxf(wmax, __shfl_xor(wmax, 32));
  if (jr == 0) redmax[w][hl] = wmax;
  __syncthreads();
  float gm = fmaxf(fmaxf(redmax[0][hl], redmax[1][hl]),
                   fmaxf(redmax[2][hl], redmax[3][hl]));

  float e[4], es = 0.f;
#pragma unroll
  for (int r = 0; r < 4; r++){ e[r] = __expf(s[r] - gm); es += e[r]; }
  es += __shfl_xor(es, 16);
  es += __shfl_xor(es, 32);
  if (jr == 0) redsum[w][hl] = es;
  __syncthreads();
  float S = redsum[0][hl] + redsum[1][hl] + redsum[2][hl] + redsum[3][hl];
  float invS = 1.0f / S;

  float4 t4 = *(const float4*)(tsc + be*64 + w*16 + jr*4);
  if (hl < 12){
    float4 pv = make_float4(e[0]*invS*t4.x, e[1]*invS*t4.y,
                            e[2]*invS*t4.z, e[3]*invS*t4.w);
    *(float4*)(probs + (size_t)be*768 + hl*64 + w*16 + jr*4) = pv;
  }
}

// ---------------------------------------------------------------------------
// Kernel B: u[h][c] = sum_j P[h][j] v_in[j][c]  -> U bf16 [h][be][c] planes
//           ps[h]   = sum_j P[h][j]             -> ps_g[be][12]
// 384 threads, 2 cols/thread, LDS = P only (3 KB)
// ---------------------------------------------------------------------------
__global__ __launch_bounds__(384)
void attn_u(const float* __restrict__ v_in, const float* __restrict__ probs,
            ushort_t* __restrict__ Ug, float* __restrict__ ps_g)
{
  const int be = blockIdx.x;
  const int t = threadIdx.x;

  __shared__ float P[12][64];

  ((float*)P)[t]       = probs[(size_t)be*768 + t];
  ((float*)P)[t + 384] = probs[(size_t)be*768 + t + 384];
  __syncthreads();

  if (t < 12){
    float s = 0.f;
#pragma unroll
    for (int jb = 0; jb < 16; jb++){
      float4 p4 = *(const float4*)&P[t][jb*4];
      s += p4.x + p4.y + p4.z + p4.w;
    }
    ps_g[be*12 + t] = s;
  }

  const float* vbase = v_in + (size_t)be*Kdim*768 + 2*t;
  float u0[12], u1[12];
#pragma unroll
  for (int h = 0; h < 12; h++){ u0[h] = 0.f; u1[h] = 0.f; }

  for (int jb = 0; jb < 16; jb++){
    float2 v[4];
#pragma unroll
    for (int q = 0; q < 4; q++)
      v[q] = *(const float2*)(vbase + (size_t)(jb*4 + q)*768);
#pragma unroll
    for (int h = 0; h < 12; h++){
      float4 p4 = *(const float4*)&P[h][jb*4];
      u0[h] += p4.x*v[0].x + p4.y*v[1].x + p4.z*v[2].x + p4.w*v[3].x;
      u1[h] += p4.x*v[0].y + p4.y*v[1].y + p4.z*v[2].y + p4.w*v[3].y;
    }
  }

#pragma unroll
  for (int h = 0; h < 12; h++){
    u32 word = (u32)f2bf(u0[h]) | ((u32)f2bf(u1[h]) << 16);
    ((u32*)(Ug + (size_t)h*GPLANE + (size_t)be*768))[t] = word;
  }
}

// ---------------------------------------------------------------------------
// Kernel C: out[be][h*64+o'] = U[h][be][:]·Wv[h*64+o'][:] + bv*ps
// per (head, 128-be tile): [128x768]·[768x64] MFMA GEMM, no LDS
// ---------------------------------------------------------------------------
__global__ __launch_bounds__(256)
void out_proj(const ushort_t* __restrict__ Ug, const ushort_t* __restrict__ Wvb,
              const float* __restrict__ bv, const float* __restrict__ ps_g,
              float* __restrict__ out)
{
  const int h  = blockIdx.y;
  const int m0 = blockIdx.x * 128;
  const int t = threadIdx.x, lane = t & 63, wave = t >> 6;
  const int wm = wave >> 1, wn = wave & 1;
  const int hl = lane & 15, jr = lane >> 4;

  const ushort_t* Up = Ug + (size_t)h*GPLANE;

  floatx4 acc[4][2];
#pragma unroll
  for (int i = 0; i < 4; i++){ acc[i][0] = (floatx4)0.f; acc[i][1] = (floatx4)0.f; }

#pragma unroll 4
  for (int kt = 0; kt < 24; kt++){
    short8 af[4], bf[2];
#pragma unroll
    for (int mi = 0; mi < 4; mi++)
      af[mi] = *(const short8*)(Up + (size_t)(m0 + wm*64 + mi*16 + hl)*768 + kt*32 + jr*8);
#pragma unroll
    for (int ni = 0; ni < 2; ni++)
      bf[ni] = *(const short8*)(Wvb + (size_t)(h*64 + wn*32 + ni*16 + hl)*768 + kt*32 + jr*8);
#pragma unroll
    for (int mi = 0; mi < 4; mi++)
#pragma unroll
      for (int ni = 0; ni < 2; ni++)
        acc[mi][ni] = __builtin_amdgcn_mfma_f32_16x16x32_bf16(af[mi], bf[ni], acc[mi][ni], 0, 0, 0);
  }

  float bvo[2];
#pragma unroll
  for (int ni = 0; ni < 2; ni++) bvo[ni] = bv[h*64 + wn*32 + ni*16 + hl];

#pragma unroll
  for (int mi = 0; mi < 4; mi++){
#pragma unroll
    for (int r = 0; r < 4; r++){
      int be = m0 + wm*64 + mi*16 + jr*4 + r;
      float psv = ps_g[be*12 + h];
#pragma unroll
      for (int ni = 0; ni < 2; ni++)
        out[(size_t)be*768 + h*64 + wn*32 + ni*16 + hl] = acc[mi][ni][r] + bvo[ni]*psv;
    }
  }
}

// ---------------------------------------------------------------------------
extern "C" void kernel_launch(void* const* d_in, const int* in_sizes, int n_in,
                              void* d_out, int out_size, void* d_ws, size_t ws_size,
                              hipStream_t stream)
{
  const float* q_in = (const float*)d_in[0];
  const float* k_in = (const float*)d_in[1];
  const float* v_in = (const float*)d_in[2];
  const float* tsc  = (const float*)d_in[3];
  const float* Wq   = (const float*)d_in[4];
  const float* bq   = (const float*)d_in[5];
  const float* Wk   = (const float*)d_in[6];
  // bk dropped (softmax-invariant)
  const float* Wv   = (const float*)d_in[8];
  const float* bv   = (const float*)d_in[9];

  // ws layout (bytes):
  //   0         Wq bf16    1179648
  //   1179648   Wv bf16    1179648
  //   2359296   WkT bf16   1179648
  //   3538944   qp bf16    3145728   (2048 x 768)
  //   6684672   g bf16     37748736  (12 x 2048 x 768)
  //   44433408  U bf16     37748736  (12 x 2048 x 768)
  //   82182144  ps fp32    98304     (2048 x 12)
  //   82280448  probs f32  6291456   (2048 x 768)
  // total ~88.6 MiB
  char* ws = (char*)d_ws;
  ushort_t* Wqb  = (ushort_t*)(ws);
  ushort_t* Wvb  = (ushort_t*)(ws + 1179648);
  ushort_t* WkTb = (ushort_t*)(ws + 2359296);
  ushort_t* qp   = (ushort_t*)(ws + 3538944);
  ushort_t* g    = (ushort_t*)(ws + 6684672);
  ushort_t* Ug   = (ushort_t*)(ws + 44433408);
  float*    ps_g = (float*)   (ws + 82182144);
  float*    probs= (float*)   (ws + 82280448);

  cvt_w <<<576, 256, 0, stream>>>(Wq, Wqb);
  cvt_w <<<576, 256, 0, stream>>>(Wv, Wvb);
  cvt_wT<<<dim3(24, 24), 256, 0, stream>>>(Wk, WkTb);

  // qp = q_in @ Wq^T + bq (bf16), M=2048
  gemm_proj<1><<<dim3(6, 16), 256, 0, stream>>>(q_in, Wqb, bq, (void*)qp);

  // g[h] = qp_h @ Wk_h (per-head, K=64)
  gemm_g<<<dim3(6, 16, 12), 256, 0, stream>>>(qp, WkTb, g);

  // A: scores + softmax * type -> probs
  attn_scores<<<2048, 256, 0, stream>>>(k_in, tsc, g, probs);

  // B: u-phase -> U (bf16 planes) + ps
  attn_u<<<2048, 384, 0, stream>>>(v_in, probs, Ug, ps_g);

  // C: out-projection GEMM
  out_proj<<<dim3(16, 12), 256, 0, stream>>>(Ug, Wvb, bv, ps_g, (float*)d_out);
}

// Round 6
// 268.248 us; speedup vs baseline: 3.3370x; 1.0053x over previous
//
#include <hip/hip_runtime.h>
#include <stdint.h>

// Problem constants
#define Bdim  8
#define Edim  256
#define Kdim  64
#define Hdim  768
#define NHdim 12
#define HDdim 64
// BE = 2048

typedef __attribute__((ext_vector_type(8))) short short8;
typedef __attribute__((ext_vector_type(4))) float floatx4;
typedef unsigned short ushort_t;
typedef unsigned int u32;

#define GPLANE (2048*768)   // per-head plane stride (elements) for g and U

__device__ __forceinline__ float bf2f(ushort_t u){
  union { u32 i; float f; } v; v.i = ((u32)u) << 16; return v.f;
}
__device__ __forceinline__ ushort_t f2bf(float f){
  union { float f; u32 i; } v; v.f = f;
  u32 r = v.i + 0x7fffu + ((v.i >> 16) & 1u);   // RNE
  return (ushort_t)(r >> 16);
}
// packed 2xfp32 -> 2xbf16 (RNE), gfx950 v_cvt_pk_bf16_f32 (T12 primitive)
__device__ __forceinline__ u32 cvtpk(float lo, float hi){
  u32 r;
  asm("v_cvt_pk_bf16_f32 %0, %1, %2" : "=v"(r) : "v"(lo), "v"(hi));
  return r;
}

// async global->LDS 16B (dest: wave-uniform base + lane*16)
__device__ __forceinline__ void async_ld16(void* lds, const void* g){
  __builtin_amdgcn_global_load_lds(
      (const __attribute__((address_space(1))) u32*)(uintptr_t)g,
      (__attribute__((address_space(3))) u32*)(u32)(uintptr_t)lds,
      16, 0, 0);
}

// ---------------------------------------------------------------------------
// GEMM (verified): C[M][768] = A[M][768](fp32) @ W^T(bf16) + bias, bf16 out
// ---------------------------------------------------------------------------
__global__ __launch_bounds__(256, 2)
void gemm_proj(const float* __restrict__ A, const ushort_t* __restrict__ W,
               const float* __restrict__ bias, ushort_t* __restrict__ Cout)
{
  __shared__ __align__(16) char smem[34816];
  const int t    = threadIdx.x;
  const int lane = t & 63;
  const int wave = t >> 6;
  const int wm   = wave >> 1, wn = wave & 1;
  const int n0   = blockIdx.x * 128;
  const int m0   = blockIdx.y * 128;

  floatx4 acc[4][4];
#pragma unroll
  for (int i = 0; i < 4; i++)
#pragma unroll
    for (int j = 0; j < 4; j++) acc[i][j] = (floatx4)0.f;

  int am[4], ac[4];
#pragma unroll
  for (int q = 0; q < 4; q++){ int idx = q*256 + t; am[q] = idx >> 3; ac[q] = idx & 7; }

  float4 areg[4];
  const int NT = Hdim / 32;

  char* const smemc = (char*)smem;
  auto Abase = [&](int b){ return smemc + b*16384; };
  auto Wbase = [&](int b){ return smemc + b*16384 + 8192; };

  auto loadA = [&](int kt){
    const float* Ap = A + (size_t)m0*768 + kt*32;
#pragma unroll
    for (int q = 0; q < 4; q++)
      areg[q] = *(const float4*)(Ap + (size_t)am[q]*768 + ac[q]*4);
  };
  auto writeA = [&](int b){
    char* base = Abase(b);
#pragma unroll
    for (int q = 0; q < 4; q++){
      u32 lo = (u32)f2bf(areg[q].x) | ((u32)f2bf(areg[q].y) << 16);
      u32 hi = (u32)f2bf(areg[q].z) | ((u32)f2bf(areg[q].w) << 16);
      int off = am[q]*64 + ((ac[q]*8) ^ ((am[q]&3) << 4));
      u32* p = (u32*)(base + off);
      p[0] = lo; p[1] = hi;
    }
  };
  auto stageW = [&](int kt, int b){
    char* base = Wbase(b);
#pragma unroll
    for (int i = 0; i < 2; i++){
      int s  = i*256 + t;
      int n  = s >> 2, kc = s & 3;
      int kcs = kc ^ (n & 3);
      const ushort_t* g = W + (size_t)(n0 + n)*768 + kt*32 + kcs*8;
      char* ldst = base + (i*256 + wave*64) * 16;
      async_ld16(ldst, g);
    }
  };
  auto compute = [&](int b){
    char* ab = Abase(b);
    char* wb = Wbase(b);
    short8 af[4], bf[4];
#pragma unroll
    for (int mi = 0; mi < 4; mi++){
      int row = wm*64 + mi*16 + (lane & 15);
      int off = row*64 + (((lane >> 4) * 16) ^ ((row & 3) << 4));
      af[mi] = *(const short8*)(ab + off);
    }
#pragma unroll
    for (int ni = 0; ni < 4; ni++){
      int row = wn*64 + ni*16 + (lane & 15);
      int off = row*64 + (((lane >> 4) * 16) ^ ((row & 3) << 4));
      bf[ni] = *(const short8*)(wb + off);
    }
#pragma unroll
    for (int mi = 0; mi < 4; mi++)
#pragma unroll
      for (int ni = 0; ni < 4; ni++)
        acc[mi][ni] = __builtin_amdgcn_mfma_f32_16x16x32_bf16(af[mi], bf[ni], acc[mi][ni], 0, 0, 0);
  };

  int buf = 0;
  loadA(0);
  stageW(0, 0);
  writeA(0);
  asm volatile("s_waitcnt vmcnt(0)" ::: "memory");
  __syncthreads();

  for (int kt = 0; kt < NT; ++kt){
    if (kt + 1 < NT){
      loadA(kt + 1);
      stageW(kt + 1, buf ^ 1);
    }
    compute(buf);
    if (kt + 1 < NT) writeA(buf ^ 1);
    asm volatile("s_waitcnt vmcnt(0)" ::: "memory");
    __syncthreads();
    buf ^= 1;
  }

  float bvv[4];
#pragma unroll
  for (int ni = 0; ni < 4; ni++) bvv[ni] = bias[n0 + wn*64 + ni*16 + (lane & 15)];

  ushort_t* sc = (ushort_t*)smem;   // [128][136] padded repack
#pragma unroll
  for (int mi = 0; mi < 4; mi++){
    int row0 = wm*64 + mi*16 + ((lane >> 4) << 2);
#pragma unroll
    for (int ni = 0; ni < 4; ni++){
      int col = wn*64 + ni*16 + (lane & 15);
#pragma unroll
      for (int r = 0; r < 4; r++)
        sc[(row0 + r)*136 + col] = f2bf(acc[mi][ni][r] + bvv[ni]);
    }
  }
  __syncthreads();
  int row = t >> 1, seg = t & 1;
  const char* src = smemc + row*272 + seg*128;
  char* dst = (char*)(Cout + (size_t)(m0 + row)*768 + n0 + seg*64);
#pragma unroll
  for (int c = 0; c < 8; c++)
    *(floatx4*)(dst + c*16) = *(const floatx4*)(src + c*16);
}

// ---------------------------------------------------------------------------
// prep: one kernel, 3 grid sections
//   blocks [0,576)    : Wq fp32 -> bf16
//   blocks [576,1152) : Wv fp32 -> bf16
//   blocks [1152,1728): WkT transpose+convert (O[c][o] = bf16(Wk[o][c]))
// ---------------------------------------------------------------------------
__global__ __launch_bounds__(256)
void prep(const float* __restrict__ Wq, const float* __restrict__ Wv,
          const float* __restrict__ Wk, ushort_t* __restrict__ Wqb,
          ushort_t* __restrict__ Wvb, ushort_t* __restrict__ WkTb)
{
  __shared__ float tile[32][33];
  const int b = blockIdx.x;
  if (b < 1152){
    const float* src = (b < 576) ? Wq : Wv;
    ushort_t*    dst = (b < 576) ? Wqb : Wvb;
    int bb = (b < 576) ? b : b - 576;
    int i = (bb * 256 + threadIdx.x) * 4;
    float4 v = *(const float4*)(src + i);
    u32* p = (u32*)(dst + i);
    p[0] = (u32)f2bf(v.x) | ((u32)f2bf(v.y) << 16);
    p[1] = (u32)f2bf(v.z) | ((u32)f2bf(v.w) << 16);
  } else {
    int bb = b - 1152;
    int bo = (bb / 24) * 32;
    int bc = (bb % 24) * 32;
    int tx = threadIdx.x & 31, ty = threadIdx.x >> 5;
#pragma unroll
    for (int i = 0; i < 4; i++)
      tile[ty + 8*i][tx] = Wk[(size_t)(bo + ty + 8*i)*768 + bc + tx];
    __syncthreads();
#pragma unroll
    for (int i = 0; i < 4; i++)
      WkTb[(size_t)(bc + ty + 8*i)*768 + bo + tx] = f2bf(tile[tx][ty + 8*i]);
  }
}

// ---------------------------------------------------------------------------
// g[h][be][c] = sum_d qp[be][h*64+d] * WkT[c][h*64+d]   (bf16, K=64)
// ---------------------------------------------------------------------------
__global__ __launch_bounds__(256)
void gemm_g(const ushort_t* __restrict__ qp, const ushort_t* __restrict__ WkT,
            ushort_t* __restrict__ g)
{
  const int h  = blockIdx.z;
  const int n0 = blockIdx.x * 128;
  const int m0 = blockIdx.y * 128;
  const int t = threadIdx.x, lane = t & 63, wave = t >> 6;
  const int wm = wave >> 1, wn = wave & 1;
  const int hl = lane & 15, jr = lane >> 4;

  floatx4 acc[4][4];
#pragma unroll
  for (int i = 0; i < 4; i++)
#pragma unroll
    for (int j = 0; j < 4; j++) acc[i][j] = (floatx4)0.f;

#pragma unroll
  for (int kt = 0; kt < 2; kt++){
    short8 af[4], bf[4];
#pragma unroll
    for (int mi = 0; mi < 4; mi++)
      af[mi] = *(const short8*)(qp + (size_t)(m0 + wm*64 + mi*16 + hl)*768 + h*64 + kt*32 + jr*8);
#pragma unroll
    for (int ni = 0; ni < 4; ni++)
      bf[ni] = *(const short8*)(WkT + (size_t)(n0 + wn*64 + ni*16 + hl)*768 + h*64 + kt*32 + jr*8);
#pragma unroll
    for (int mi = 0; mi < 4; mi++)
#pragma unroll
      for (int ni = 0; ni < 4; ni++)
        acc[mi][ni] = __builtin_amdgcn_mfma_f32_16x16x32_bf16(af[mi], bf[ni], acc[mi][ni], 0, 0, 0);
  }

  ushort_t* gp = g + (size_t)h * GPLANE;
#pragma unroll
  for (int mi = 0; mi < 4; mi++){
#pragma unroll
    for (int ni = 0; ni < 4; ni++){
      int col = n0 + wn*64 + ni*16 + hl;
#pragma unroll
      for (int r = 0; r < 4; r++){
        int row = m0 + wm*64 + mi*16 + jr*4 + r;
        gp[(size_t)row*768 + col] = f2bf(acc[mi][ni][r]);
      }
    }
  }
}

// ---------------------------------------------------------------------------
// attn_main: fused scores+softmax*type (waves 0-3, MFMA) then u-phase (all).
// one block per be, 384 threads, LDS ~3.4 KB.
//   P[h][j]  = softmax_j(k[j,:]·g[h,:]/8) * type[j]
//   U[h][c]  = sum_j P[h][j] v[j][c]  -> bf16 planes [h][be][c]
//   ps[h]    = sum_j P[h][j]
// ---------------------------------------------------------------------------
__global__ __launch_bounds__(384)
void attn_main(const float* __restrict__ k_in, const float* __restrict__ v_in,
               const float* __restrict__ tsc, const ushort_t* __restrict__ g,
               ushort_t* __restrict__ Ug, float* __restrict__ ps_g)
{
  const int be = blockIdx.x;
  const int t = threadIdx.x, lane = t & 63, w = t >> 6;
  const int hl = lane & 15, jr = lane >> 4;

  __shared__ float P[12][64];
  __shared__ float redmax[4][16];
  __shared__ float redsum[4][16];

  // ---- phase A: scores + softmax (waves 0-3) ----
  float s[4], e[4], gm;
  if (w < 4){
    const float* krow = k_in + (size_t)be*Kdim*768 + (size_t)(w*16 + hl)*768;
    const int hq = (hl < 12) ? hl : 0;
    const ushort_t* grow = g + (size_t)hq*GPLANE + (size_t)be*768;

    floatx4 acc = (floatx4)0.f;
#pragma unroll 4
    for (int kt = 0; kt < 24; kt++){
      int c0 = kt*32 + jr*8;
      float4 f0 = *(const float4*)(krow + c0);
      float4 f1 = *(const float4*)(krow + c0 + 4);
      union { short8 s8; u32 wd[4]; } A;
      A.wd[0] = cvtpk(f0.x, f0.y);
      A.wd[1] = cvtpk(f0.z, f0.w);
      A.wd[2] = cvtpk(f1.x, f1.y);
      A.wd[3] = cvtpk(f1.z, f1.w);
      short8 bf = *(const short8*)(grow + c0);
      acc = __builtin_amdgcn_mfma_f32_16x16x32_bf16(A.s8, bf, acc, 0, 0, 0);
    }
#pragma unroll
    for (int r = 0; r < 4; r++) s[r] = acc[r] * 0.125f;

    float wmax = fmaxf(fmaxf(s[0], s[1]), fmaxf(s[2], s[3]));
    wmax = fmaxf(wmax, __shfl_xor(wmax, 16));
    wmax = fmaxf(wmax, __shfl_xor(wmax, 32));
    if (jr == 0) redmax[w][hl] = wmax;
  }
  __syncthreads();
  if (w < 4){
    gm = fmaxf(fmaxf(redmax[0][hl], redmax[1][hl]),
               fmaxf(redmax[2][hl], redmax[3][hl]));
    float es = 0.f;
#pragma unroll
    for (int r = 0; r < 4; r++){ e[r] = __expf(s[r] - gm); es += e[r]; }
    es += __shfl_xor(es, 16);
    es += __shfl_xor(es, 32);
    if (jr == 0) redsum[w][hl] = es;
  }
  __syncthreads();
  if (w < 4 && hl < 12){
    float S = redsum[0][hl] + redsum[1][hl] + redsum[2][hl] + redsum[3][hl];
    float invS = 1.0f / S;
    float4 t4 = *(const float4*)(tsc + be*64 + w*16 + jr*4);
    float4 pv = make_float4(e[0]*invS*t4.x, e[1]*invS*t4.y,
                            e[2]*invS*t4.z, e[3]*invS*t4.w);
    *(float4*)&P[hl][w*16 + jr*4] = pv;
  }
  __syncthreads();

  // ---- ps (12 threads) ----
  if (t < 12){
    float sum = 0.f;
#pragma unroll
    for (int jb = 0; jb < 16; jb++){
      float4 p4 = *(const float4*)&P[t][jb*4];
      sum += p4.x + p4.y + p4.z + p4.w;
    }
    ps_g[be*12 + t] = sum;
  }

  // ---- phase B: u (all 384 threads, 2 cols each) ----
  const float* vbase = v_in + (size_t)be*Kdim*768 + 2*t;
  float u0[12], u1[12];
#pragma unroll
  for (int h = 0; h < 12; h++){ u0[h] = 0.f; u1[h] = 0.f; }

  for (int jb = 0; jb < 16; jb++){
    float2 v[4];
#pragma unroll
    for (int q = 0; q < 4; q++)
      v[q] = *(const float2*)(vbase + (size_t)(jb*4 + q)*768);
#pragma unroll
    for (int h = 0; h < 12; h++){
      float4 p4 = *(const float4*)&P[h][jb*4];
      u0[h] += p4.x*v[0].x + p4.y*v[1].x + p4.z*v[2].x + p4.w*v[3].x;
      u1[h] += p4.x*v[0].y + p4.y*v[1].y + p4.z*v[2].y + p4.w*v[3].y;
    }
  }

#pragma unroll
  for (int h = 0; h < 12; h++)
    ((u32*)(Ug + (size_t)h*GPLANE + (size_t)be*768))[t] = cvtpk(u0[h], u1[h]);
}

// ---------------------------------------------------------------------------
// out_proj: out[be][h*64+o'] = U[h][be][:]·Wv[h*64+o'][:] + bv*ps
// per (head, 128-be tile): [128x768]·[768x64] MFMA GEMM, no LDS
// ---------------------------------------------------------------------------
__global__ __launch_bounds__(256)
void out_proj(const ushort_t* __restrict__ Ug, const ushort_t* __restrict__ Wvb,
              const float* __restrict__ bv, const float* __restrict__ ps_g,
              float* __restrict__ out)
{
  const int h  = blockIdx.y;
  const int m0 = blockIdx.x * 128;
  const int t = threadIdx.x, lane = t & 63, wave = t >> 6;
  const int wm = wave >> 1, wn = wave & 1;
  const int hl = lane & 15, jr = lane >> 4;

  const ushort_t* Up = Ug + (size_t)h*GPLANE;

  floatx4 acc[4][2];
#pragma unroll
  for (int i = 0; i < 4; i++){ acc[i][0] = (floatx4)0.f; acc[i][1] = (floatx4)0.f; }

#pragma unroll 4
  for (int kt = 0; kt < 24; kt++){
    short8 af[4], bf[2];
#pragma unroll
    for (int mi = 0; mi < 4; mi++)
      af[mi] = *(const short8*)(Up + (size_t)(m0 + wm*64 + mi*16 + hl)*768 + kt*32 + jr*8);
#pragma unroll
    for (int ni = 0; ni < 2; ni++)
      bf[ni] = *(const short8*)(Wvb + (size_t)(h*64 + wn*32 + ni*16 + hl)*768 + kt*32 + jr*8);
#pragma unroll
    for (int mi = 0; mi < 4; mi++)
#pragma unroll
      for (int ni = 0; ni < 2; ni++)
        acc[mi][ni] = __builtin_amdgcn_mfma_f32_16x16x32_bf16(af[mi], bf[ni], acc[mi][ni], 0, 0, 0);
  }

  float bvo[2];
#pragma unroll
  for (int ni = 0; ni < 2; ni++) bvo[ni] = bv[h*64 + wn*32 + ni*16 + hl];

#pragma unroll
  for (int mi = 0; mi < 4; mi++){
#pragma unroll
    for (int r = 0; r < 4; r++){
      int be = m0 + wm*64 + mi*16 + jr*4 + r;
      float psv = ps_g[be*12 + h];
#pragma unroll
      for (int ni = 0; ni < 2; ni++)
        out[(size_t)be*768 + h*64 + wn*32 + ni*16 + hl] = acc[mi][ni][r] + bvo[ni]*psv;
    }
  }
}

// ---------------------------------------------------------------------------
extern "C" void kernel_launch(void* const* d_in, const int* in_sizes, int n_in,
                              void* d_out, int out_size, void* d_ws, size_t ws_size,
                              hipStream_t stream)
{
  const float* q_in = (const float*)d_in[0];
  const float* k_in = (const float*)d_in[1];
  const float* v_in = (const float*)d_in[2];
  const float* tsc  = (const float*)d_in[3];
  const float* Wq   = (const float*)d_in[4];
  const float* bq   = (const float*)d_in[5];
  const float* Wk   = (const float*)d_in[6];
  // bk dropped (softmax-invariant)
  const float* Wv   = (const float*)d_in[8];
  const float* bv   = (const float*)d_in[9];

  // ws layout (bytes):
  //   0         Wq bf16    1179648
  //   1179648   Wv bf16    1179648
  //   2359296   WkT bf16   1179648
  //   3538944   qp bf16    3145728   (2048 x 768)
  //   6684672   g bf16     37748736  (12 x 2048 x 768)
  //   44433408  U bf16     37748736  (12 x 2048 x 768)
  //   82182144  ps fp32    98304     (2048 x 12)
  // total ~78.5 MiB
  char* ws = (char*)d_ws;
  ushort_t* Wqb  = (ushort_t*)(ws);
  ushort_t* Wvb  = (ushort_t*)(ws + 1179648);
  ushort_t* WkTb = (ushort_t*)(ws + 2359296);
  ushort_t* qp   = (ushort_t*)(ws + 3538944);
  ushort_t* g    = (ushort_t*)(ws + 6684672);
  ushort_t* Ug   = (ushort_t*)(ws + 44433408);
  float*    ps_g = (float*)   (ws + 82182144);

  // 1: all weight converts in one kernel
  prep<<<1728, 256, 0, stream>>>(Wq, Wv, Wk, Wqb, Wvb, WkTb);

  // 2: qp = q_in @ Wq^T + bq (bf16), M=2048
  gemm_proj<<<dim3(6, 16), 256, 0, stream>>>(q_in, Wqb, bq, qp);

  // 3: g[h] = qp_h @ Wk_h (per-head, K=64)
  gemm_g<<<dim3(6, 16, 12), 256, 0, stream>>>(qp, WkTb, g);

  // 4: fused scores+softmax+u
  attn_main<<<2048, 384, 0, stream>>>(k_in, v_in, tsc, g, Ug, ps_g);

  // 5: out-projection GEMM
  out_proj<<<dim3(16, 12), 256, 0, stream>>>(Ug, Wvb, bv, ps_g, (float*)d_out);
}

// Round 7
// 263.569 us; speedup vs baseline: 3.3963x; 1.0178x over previous
//
#include <hip/hip_runtime.h>
#include <stdint.h>

// Problem constants
#define Bdim  8
#define Edim  256
#define Kdim  64
#define Hdim  768
#define NHdim 12
#define HDdim 64
// BE = 2048

typedef __attribute__((ext_vector_type(8))) short short8;
typedef __attribute__((ext_vector_type(4))) float floatx4;
typedef unsigned short ushort_t;
typedef unsigned int u32;

#define GPLANE (2048*768)   // per-head plane stride (elements) for g and U

__device__ __forceinline__ float bf2f(ushort_t u){
  union { u32 i; float f; } v; v.i = ((u32)u) << 16; return v.f;
}
__device__ __forceinline__ ushort_t f2bf(float f){
  union { float f; u32 i; } v; v.f = f;
  u32 r = v.i + 0x7fffu + ((v.i >> 16) & 1u);   // RNE
  return (ushort_t)(r >> 16);
}
// packed 2xfp32 -> 2xbf16 (RNE), gfx950 v_cvt_pk_bf16_f32
__device__ __forceinline__ u32 cvtpk(float lo, float hi){
  u32 r;
  asm("v_cvt_pk_bf16_f32 %0, %1, %2" : "=v"(r) : "v"(lo), "v"(hi));
  return r;
}

// async global->LDS 16B (dest: wave-uniform base + lane*16)
__device__ __forceinline__ void async_ld16(void* lds, const void* g){
  __builtin_amdgcn_global_load_lds(
      (const __attribute__((address_space(1))) u32*)(uintptr_t)g,
      (__attribute__((address_space(3))) u32*)(u32)(uintptr_t)lds,
      16, 0, 0);
}

// ---------------------------------------------------------------------------
// GEMM (verified): C[M][768] = A[M][768](fp32) @ W^T(bf16) + bias, bf16 out
// ---------------------------------------------------------------------------
__global__ __launch_bounds__(256, 2)
void gemm_proj(const float* __restrict__ A, const ushort_t* __restrict__ W,
               const float* __restrict__ bias, ushort_t* __restrict__ Cout)
{
  __shared__ __align__(16) char smem[34816];
  const int t    = threadIdx.x;
  const int lane = t & 63;
  const int wave = t >> 6;
  const int wm   = wave >> 1, wn = wave & 1;
  const int n0   = blockIdx.x * 128;
  const int m0   = blockIdx.y * 128;

  floatx4 acc[4][4];
#pragma unroll
  for (int i = 0; i < 4; i++)
#pragma unroll
    for (int j = 0; j < 4; j++) acc[i][j] = (floatx4)0.f;

  int am[4], ac[4];
#pragma unroll
  for (int q = 0; q < 4; q++){ int idx = q*256 + t; am[q] = idx >> 3; ac[q] = idx & 7; }

  float4 areg[4];
  const int NT = Hdim / 32;

  char* const smemc = (char*)smem;
  auto Abase = [&](int b){ return smemc + b*16384; };
  auto Wbase = [&](int b){ return smemc + b*16384 + 8192; };

  auto loadA = [&](int kt){
    const float* Ap = A + (size_t)m0*768 + kt*32;
#pragma unroll
    for (int q = 0; q < 4; q++)
      areg[q] = *(const float4*)(Ap + (size_t)am[q]*768 + ac[q]*4);
  };
  auto writeA = [&](int b){
    char* base = Abase(b);
#pragma unroll
    for (int q = 0; q < 4; q++){
      u32 lo = (u32)f2bf(areg[q].x) | ((u32)f2bf(areg[q].y) << 16);
      u32 hi = (u32)f2bf(areg[q].z) | ((u32)f2bf(areg[q].w) << 16);
      int off = am[q]*64 + ((ac[q]*8) ^ ((am[q]&3) << 4));
      u32* p = (u32*)(base + off);
      p[0] = lo; p[1] = hi;
    }
  };
  auto stageW = [&](int kt, int b){
    char* base = Wbase(b);
#pragma unroll
    for (int i = 0; i < 2; i++){
      int s  = i*256 + t;
      int n  = s >> 2, kc = s & 3;
      int kcs = kc ^ (n & 3);
      const ushort_t* g = W + (size_t)(n0 + n)*768 + kt*32 + kcs*8;
      char* ldst = base + (i*256 + wave*64) * 16;
      async_ld16(ldst, g);
    }
  };
  auto compute = [&](int b){
    char* ab = Abase(b);
    char* wb = Wbase(b);
    short8 af[4], bf[4];
#pragma unroll
    for (int mi = 0; mi < 4; mi++){
      int row = wm*64 + mi*16 + (lane & 15);
      int off = row*64 + (((lane >> 4) * 16) ^ ((row & 3) << 4));
      af[mi] = *(const short8*)(ab + off);
    }
#pragma unroll
    for (int ni = 0; ni < 4; ni++){
      int row = wn*64 + ni*16 + (lane & 15);
      int off = row*64 + (((lane >> 4) * 16) ^ ((row & 3) << 4));
      bf[ni] = *(const short8*)(wb + off);
    }
#pragma unroll
    for (int mi = 0; mi < 4; mi++)
#pragma unroll
      for (int ni = 0; ni < 4; ni++)
        acc[mi][ni] = __builtin_amdgcn_mfma_f32_16x16x32_bf16(af[mi], bf[ni], acc[mi][ni], 0, 0, 0);
  };

  int buf = 0;
  loadA(0);
  stageW(0, 0);
  writeA(0);
  asm volatile("s_waitcnt vmcnt(0)" ::: "memory");
  __syncthreads();

  for (int kt = 0; kt < NT; ++kt){
    if (kt + 1 < NT){
      loadA(kt + 1);
      stageW(kt + 1, buf ^ 1);
    }
    compute(buf);
    if (kt + 1 < NT) writeA(buf ^ 1);
    asm volatile("s_waitcnt vmcnt(0)" ::: "memory");
    __syncthreads();
    buf ^= 1;
  }

  float bvv[4];
#pragma unroll
  for (int ni = 0; ni < 4; ni++) bvv[ni] = bias[n0 + wn*64 + ni*16 + (lane & 15)];

  ushort_t* sc = (ushort_t*)smem;   // [128][136] padded repack
#pragma unroll
  for (int mi = 0; mi < 4; mi++){
    int row0 = wm*64 + mi*16 + ((lane >> 4) << 2);
#pragma unroll
    for (int ni = 0; ni < 4; ni++){
      int col = wn*64 + ni*16 + (lane & 15);
#pragma unroll
      for (int r = 0; r < 4; r++)
        sc[(row0 + r)*136 + col] = f2bf(acc[mi][ni][r] + bvv[ni]);
    }
  }
  __syncthreads();
  int row = t >> 1, seg = t & 1;
  const char* src = smemc + row*272 + seg*128;
  char* dst = (char*)(Cout + (size_t)(m0 + row)*768 + n0 + seg*64);
#pragma unroll
  for (int c = 0; c < 8; c++)
    *(floatx4*)(dst + c*16) = *(const floatx4*)(src + c*16);
}

// ---------------------------------------------------------------------------
// prep: Wq cvt | Wv cvt | WkT transpose+cvt, one kernel
// ---------------------------------------------------------------------------
__global__ __launch_bounds__(256)
void prep(const float* __restrict__ Wq, const float* __restrict__ Wv,
          const float* __restrict__ Wk, ushort_t* __restrict__ Wqb,
          ushort_t* __restrict__ Wvb, ushort_t* __restrict__ WkTb)
{
  __shared__ float tile[32][33];
  const int b = blockIdx.x;
  if (b < 1152){
    const float* src = (b < 576) ? Wq : Wv;
    ushort_t*    dst = (b < 576) ? Wqb : Wvb;
    int bb = (b < 576) ? b : b - 576;
    int i = (bb * 256 + threadIdx.x) * 4;
    float4 v = *(const float4*)(src + i);
    u32* p = (u32*)(dst + i);
    p[0] = (u32)f2bf(v.x) | ((u32)f2bf(v.y) << 16);
    p[1] = (u32)f2bf(v.z) | ((u32)f2bf(v.w) << 16);
  } else {
    int bb = b - 1152;
    int bo = (bb / 24) * 32;
    int bc = (bb % 24) * 32;
    int tx = threadIdx.x & 31, ty = threadIdx.x >> 5;
#pragma unroll
    for (int i = 0; i < 4; i++)
      tile[ty + 8*i][tx] = Wk[(size_t)(bo + ty + 8*i)*768 + bc + tx];
    __syncthreads();
#pragma unroll
    for (int i = 0; i < 4; i++)
      WkTb[(size_t)(bc + ty + 8*i)*768 + bo + tx] = f2bf(tile[tx][ty + 8*i]);
  }
}

// ---------------------------------------------------------------------------
// g[h][be][c] = sum_d qp[be][h*64+d] * WkT[c][h*64+d]   (bf16, K=64)
// ---------------------------------------------------------------------------
__global__ __launch_bounds__(256)
void gemm_g(const ushort_t* __restrict__ qp, const ushort_t* __restrict__ WkT,
            ushort_t* __restrict__ g)
{
  const int h  = blockIdx.z;
  const int n0 = blockIdx.x * 128;
  const int m0 = blockIdx.y * 128;
  const int t = threadIdx.x, lane = t & 63, wave = t >> 6;
  const int wm = wave >> 1, wn = wave & 1;
  const int hl = lane & 15, jr = lane >> 4;

  floatx4 acc[4][4];
#pragma unroll
  for (int i = 0; i < 4; i++)
#pragma unroll
    for (int j = 0; j < 4; j++) acc[i][j] = (floatx4)0.f;

#pragma unroll
  for (int kt = 0; kt < 2; kt++){
    short8 af[4], bf[4];
#pragma unroll
    for (int mi = 0; mi < 4; mi++)
      af[mi] = *(const short8*)(qp + (size_t)(m0 + wm*64 + mi*16 + hl)*768 + h*64 + kt*32 + jr*8);
#pragma unroll
    for (int ni = 0; ni < 4; ni++)
      bf[ni] = *(const short8*)(WkT + (size_t)(n0 + wn*64 + ni*16 + hl)*768 + h*64 + kt*32 + jr*8);
#pragma unroll
    for (int mi = 0; mi < 4; mi++)
#pragma unroll
      for (int ni = 0; ni < 4; ni++)
        acc[mi][ni] = __builtin_amdgcn_mfma_f32_16x16x32_bf16(af[mi], bf[ni], acc[mi][ni], 0, 0, 0);
  }

  ushort_t* gp = g + (size_t)h * GPLANE;
#pragma unroll
  for (int mi = 0; mi < 4; mi++){
#pragma unroll
    for (int ni = 0; ni < 4; ni++){
      int col = n0 + wn*64 + ni*16 + hl;
#pragma unroll
      for (int r = 0; r < 4; r++){
        int row = m0 + wm*64 + mi*16 + jr*4 + r;
        gp[(size_t)row*768 + col] = f2bf(acc[mi][ni][r]);
      }
    }
  }
}

// ---------------------------------------------------------------------------
// attn_scores: scores + softmax*type -> probs[be][h][64]
// g staged in LDS (padded); explicit k-load rotation for load-ahead.
// 256 threads, LDS ~19 KB -> 8 blocks/CU.
// ---------------------------------------------------------------------------
__global__ __launch_bounds__(256)
void attn_scores(const float* __restrict__ k_in, const float* __restrict__ tsc,
                 const ushort_t* __restrict__ g, float* __restrict__ probs)
{
  const int be = blockIdx.x;
  const int t = threadIdx.x, lane = t & 63, w = t >> 6;
  const int hl = lane & 15, jr = lane >> 4;

  __shared__ __align__(16) ushort_t gs[12][776];   // stride 776 shorts = 1552 B
  __shared__ float redmax[4][16];
  __shared__ float redsum[4][16];

  // stage g rows for this be: 12 x 768 bf16 = 1152 x 16B chunks
  {
    const ushort_t* gbase = g + (size_t)be*768;
#pragma unroll
    for (int c0 = 0; c0 < 1152; c0 += 256){
      int c = c0 + t;
      if (c < 1152){
        int row = c / 96, col = (c % 96) * 8;
        *(short8*)&gs[row][col] = *(const short8*)(gbase + (size_t)row*GPLANE + col);
      }
    }
  }
  __syncthreads();

  const float* krow = k_in + (size_t)be*Kdim*768 + (size_t)(w*16 + hl)*768;
  const int hq = (hl < 12) ? hl : 0;

  floatx4 acc = (floatx4)0.f;
  float4 f0 = *(const float4*)(krow + jr*8);
  float4 f1 = *(const float4*)(krow + jr*8 + 4);
#pragma unroll 4
  for (int kt = 0; kt < 24; kt++){
    float4 nf0, nf1;
    if (kt + 1 < 24){
      int c1 = (kt + 1)*32 + jr*8;
      nf0 = *(const float4*)(krow + c1);
      nf1 = *(const float4*)(krow + c1 + 4);
    }
    union { short8 s8; u32 wd[4]; } A;
    A.wd[0] = cvtpk(f0.x, f0.y);
    A.wd[1] = cvtpk(f0.z, f0.w);
    A.wd[2] = cvtpk(f1.x, f1.y);
    A.wd[3] = cvtpk(f1.z, f1.w);
    short8 bf = *(const short8*)&gs[hq][kt*32 + jr*8];
    acc = __builtin_amdgcn_mfma_f32_16x16x32_bf16(A.s8, bf, acc, 0, 0, 0);
    f0 = nf0; f1 = nf1;
  }

  // lane holds scores[j = w*16 + jr*4 + r][h = hl]
  float s[4];
#pragma unroll
  for (int r = 0; r < 4; r++) s[r] = acc[r] * 0.125f;

  float wmax = fmaxf(fmaxf(s[0], s[1]), fmaxf(s[2], s[3]));
  wmax = fmaxf(wmax, __shfl_xor(wmax, 16));
  wmax = fmaxf(wmax, __shfl_xor(wmax, 32));
  if (jr == 0) redmax[w][hl] = wmax;
  __syncthreads();
  float gm = fmaxf(fmaxf(redmax[0][hl], redmax[1][hl]),
                   fmaxf(redmax[2][hl], redmax[3][hl]));

  float e[4], es = 0.f;
#pragma unroll
  for (int r = 0; r < 4; r++){ e[r] = __expf(s[r] - gm); es += e[r]; }
  es += __shfl_xor(es, 16);
  es += __shfl_xor(es, 32);
  if (jr == 0) redsum[w][hl] = es;
  __syncthreads();
  float S = redsum[0][hl] + redsum[1][hl] + redsum[2][hl] + redsum[3][hl];
  float invS = 1.0f / S;

  float4 t4 = *(const float4*)(tsc + be*64 + w*16 + jr*4);
  if (hl < 12){
    float4 pv = make_float4(e[0]*invS*t4.x, e[1]*invS*t4.y,
                            e[2]*invS*t4.z, e[3]*invS*t4.w);
    *(float4*)(probs + (size_t)be*768 + hl*64 + w*16 + jr*4) = pv;
  }
}

// ---------------------------------------------------------------------------
// attn_u: u[h][c] = sum_j P[h][j] v[j][c] -> U bf16 planes; ps[h] -> ps_g
// 384 threads, 2 cols/thread, explicit v-row rotation.
// ---------------------------------------------------------------------------
__global__ __launch_bounds__(384)
void attn_u(const float* __restrict__ v_in, const float* __restrict__ probs,
            ushort_t* __restrict__ Ug, float* __restrict__ ps_g)
{
  const int be = blockIdx.x;
  const int t = threadIdx.x;

  __shared__ float P[12][64];
  ((float*)P)[t]       = probs[(size_t)be*768 + t];
  ((float*)P)[t + 384] = probs[(size_t)be*768 + t + 384];
  __syncthreads();

  if (t < 12){
    float sum = 0.f;
#pragma unroll
    for (int jb = 0; jb < 16; jb++){
      float4 p4 = *(const float4*)&P[t][jb*4];
      sum += p4.x + p4.y + p4.z + p4.w;
    }
    ps_g[be*12 + t] = sum;
  }

  const float* vbase = v_in + (size_t)be*Kdim*768 + 2*t;
  float u0[12], u1[12];
#pragma unroll
  for (int h = 0; h < 12; h++){ u0[h] = 0.f; u1[h] = 0.f; }

  float2 v[4], nv[4];
#pragma unroll
  for (int q = 0; q < 4; q++)
    v[q] = *(const float2*)(vbase + (size_t)q*768);

#pragma unroll 2
  for (int jb = 0; jb < 16; jb++){
    if (jb + 1 < 16){
#pragma unroll
      for (int q = 0; q < 4; q++)
        nv[q] = *(const float2*)(vbase + (size_t)((jb+1)*4 + q)*768);
    }
#pragma unroll
    for (int h = 0; h < 12; h++){
      float4 p4 = *(const float4*)&P[h][jb*4];
      u0[h] += p4.x*v[0].x + p4.y*v[1].x + p4.z*v[2].x + p4.w*v[3].x;
      u1[h] += p4.x*v[0].y + p4.y*v[1].y + p4.z*v[2].y + p4.w*v[3].y;
    }
#pragma unroll
    for (int q = 0; q < 4; q++) v[q] = nv[q];
  }

#pragma unroll
  for (int h = 0; h < 12; h++)
    ((u32*)(Ug + (size_t)h*GPLANE + (size_t)be*768))[t] = cvtpk(u0[h], u1[h]);
}

// ---------------------------------------------------------------------------
// out_proj: out[be][h*64+o'] = U[h][be][:]·Wv[h*64+o'][:] + bv*ps
// ---------------------------------------------------------------------------
__global__ __launch_bounds__(256)
void out_proj(const ushort_t* __restrict__ Ug, const ushort_t* __restrict__ Wvb,
              const float* __restrict__ bv, const float* __restrict__ ps_g,
              float* __restrict__ out)
{
  const int h  = blockIdx.y;
  const int m0 = blockIdx.x * 128;
  const int t = threadIdx.x, lane = t & 63, wave = t >> 6;
  const int wm = wave >> 1, wn = wave & 1;
  const int hl = lane & 15, jr = lane >> 4;

  const ushort_t* Up = Ug + (size_t)h*GPLANE;

  floatx4 acc[4][2];
#pragma unroll
  for (int i = 0; i < 4; i++){ acc[i][0] = (floatx4)0.f; acc[i][1] = (floatx4)0.f; }

#pragma unroll 4
  for (int kt = 0; kt < 24; kt++){
    short8 af[4], bf[2];
#pragma unroll
    for (int mi = 0; mi < 4; mi++)
      af[mi] = *(const short8*)(Up + (size_t)(m0 + wm*64 + mi*16 + hl)*768 + kt*32 + jr*8);
#pragma unroll
    for (int ni = 0; ni < 2; ni++)
      bf[ni] = *(const short8*)(Wvb + (size_t)(h*64 + wn*32 + ni*16 + hl)*768 + kt*32 + jr*8);
#pragma unroll
    for (int mi = 0; mi < 4; mi++)
#pragma unroll
      for (int ni = 0; ni < 2; ni++)
        acc[mi][ni] = __builtin_amdgcn_mfma_f32_16x16x32_bf16(af[mi], bf[ni], acc[mi][ni], 0, 0, 0);
  }

  float bvo[2];
#pragma unroll
  for (int ni = 0; ni < 2; ni++) bvo[ni] = bv[h*64 + wn*32 + ni*16 + hl];

#pragma unroll
  for (int mi = 0; mi < 4; mi++){
#pragma unroll
    for (int r = 0; r < 4; r++){
      int be = m0 + wm*64 + mi*16 + jr*4 + r;
      float psv = ps_g[be*12 + h];
#pragma unroll
      for (int ni = 0; ni < 2; ni++)
        out[(size_t)be*768 + h*64 + wn*32 + ni*16 + hl] = acc[mi][ni][r] + bvo[ni]*psv;
    }
  }
}

// ---------------------------------------------------------------------------
extern "C" void kernel_launch(void* const* d_in, const int* in_sizes, int n_in,
                              void* d_out, int out_size, void* d_ws, size_t ws_size,
                              hipStream_t stream)
{
  const float* q_in = (const float*)d_in[0];
  const float* k_in = (const float*)d_in[1];
  const float* v_in = (const float*)d_in[2];
  const float* tsc  = (const float*)d_in[3];
  const float* Wq   = (const float*)d_in[4];
  const float* bq   = (const float*)d_in[5];
  const float* Wk   = (const float*)d_in[6];
  // bk dropped (softmax-invariant)
  const float* Wv   = (const float*)d_in[8];
  const float* bv   = (const float*)d_in[9];

  // ws layout (bytes):
  //   0         Wq bf16    1179648
  //   1179648   Wv bf16    1179648
  //   2359296   WkT bf16   1179648
  //   3538944   qp bf16    3145728   (2048 x 768)
  //   6684672   g bf16     37748736  (12 x 2048 x 768)
  //   44433408  U bf16     37748736  (12 x 2048 x 768)
  //   82182144  ps fp32    98304     (2048 x 12)
  //   82280448  probs f32  6291456   (2048 x 768)
  // total ~84.5 MiB
  char* ws = (char*)d_ws;
  ushort_t* Wqb  = (ushort_t*)(ws);
  ushort_t* Wvb  = (ushort_t*)(ws + 1179648);
  ushort_t* WkTb = (ushort_t*)(ws + 2359296);
  ushort_t* qp   = (ushort_t*)(ws + 3538944);
  ushort_t* g    = (ushort_t*)(ws + 6684672);
  ushort_t* Ug   = (ushort_t*)(ws + 44433408);
  float*    ps_g = (float*)   (ws + 82182144);
  float*    probs= (float*)   (ws + 82280448);

  prep<<<1728, 256, 0, stream>>>(Wq, Wv, Wk, Wqb, Wvb, WkTb);

  gemm_proj<<<dim3(6, 16), 256, 0, stream>>>(q_in, Wqb, bq, qp);

  gemm_g<<<dim3(6, 16, 12), 256, 0, stream>>>(qp, WkTb, g);

  attn_scores<<<2048, 256, 0, stream>>>(k_in, tsc, g, probs);

  attn_u<<<2048, 384, 0, stream>>>(v_in, probs, Ug, ps_g);

  out_proj<<<dim3(16, 12), 256, 0, stream>>>(Ug, Wvb, bv, ps_g, (float*)d_out);
}